// Round 15
// baseline (89.915 us; speedup 1.0000x reference)
//
#include <hip/hip_runtime.h>

#define TPB 256

// r29: D-elimination round on r28 (89.3us). Two more exact forwards
// (cross(e,e)=0 family, same as r28's validated pc1/pc3 identities):
//   c1(i,j+1) = c1(i,j) + ee(i,j)   -> c1 rolls across j (1 add);
//                                      row seed c1(i,0) direct (4 ops).
//   c3(i+1,j) = c3(i,j) + ee(i,j)   -> 8 persistent pc3_j roll across rows;
//                                      row-0 seed direct; j=0 seam gone:
//                                      c4(i,0) = c3(i,7) = pc3_7 at row start.
// D_x/D_y leave the steady-state pair entirely: ~-220 dyn-ops (-10%).
// Persistent set ~103 regs (<128; r27/r28 shape compiled clean).
// Everything else byte-identical to r28.
__global__ __launch_bounds__(TPB, 2) void ciou_main(
    const float* __restrict__ A,
    const float* __restrict__ Bq,
    double* __restrict__ partial,
    int nbatch, int tail)
{
    const int t = threadIdx.x;
    const int i0 = blockIdx.x * TPB + t;
    const bool live = !tail || (i0 < nbatch);
    const int i = live ? i0 : (nbatch - 1);

    float ax0,ax1,ax2,ax3,ax4,ax5,ax6,ax7;
    float ay0,ay1,ay2,ay3,ay4,ay5,ay6,ay7;
    float bx0,bx1,bx2,bx3,bx4,bx5,bx6,bx7;
    float by0,by1,by2,by3,by4,by5,by6,by7;
    {
        const float4* pa = (const float4*)(A + (size_t)i * 16);
        const float4* pb = (const float4*)(Bq + (size_t)i * 16);
        float4 q;
        q = pa[0]; ax0=q.x; ay0=q.y; ax1=q.z; ay1=q.w;
        q = pa[1]; ax2=q.x; ay2=q.y; ax3=q.z; ay3=q.w;
        q = pa[2]; ax4=q.x; ay4=q.y; ax5=q.z; ay5=q.w;
        q = pa[3]; ax6=q.x; ay6=q.y; ax7=q.z; ay7=q.w;
        q = pb[0]; bx0=q.x; by0=q.y; bx1=q.z; by1=q.w;
        q = pb[1]; bx2=q.x; by2=q.y; bx3=q.z; by3=q.w;
        q = pb[2]; bx4=q.x; by4=q.y; bx5=q.z; by5=q.w;
        q = pb[3]; bx6=q.x; by6=q.y; bx7=q.z; by7=q.w;
    }

    // B edge vectors (persistent, reused in all 64 pairs).
#define MKEB(I,IN) float ebx##I = bx##IN - bx##I, eby##I = by##IN - by##I;
    MKEB(0,1) MKEB(1,2) MKEB(2,3) MKEB(3,4)
    MKEB(4,5) MKEB(5,6) MKEB(6,7) MKEB(7,0)

    // Persistent sweep state.
    float t0b0=0.f,t0b1=0.f,t0b2=0.f,t0b3=0.f,t0b4=0.f,t0b5=0.f,t0b6=0.f,t0b7=0.f;
    float t1b0=1.f,t1b1=1.f,t1b2=1.f,t1b3=1.f,t1b4=1.f,t1b5=1.f,t1b6=1.f,t1b7=1.f;
    float mbmin0=1e38f,mbmin1=1e38f,mbmin2=1e38f,mbmin3=1e38f,
          mbmin4=1e38f,mbmin5=1e38f,mbmin6=1e38f,mbmin7=1e38f;
    float hbp = 0.f, hbm = 0.f, eSa = 0.f;
    float inter2 = 0.f, areaA2 = 0.f;

    // Seeds:
    //   pc1_j = c1(row7cyc, j) = cross(B_j - A_7, ea_7)   [c2 of row 0]
    //   pc3_j = c3(row0, j)    = cross(B_j - A_0, eb_j)   [c3 of row 0]
    float pc1_0,pc1_1,pc1_2,pc1_3,pc1_4,pc1_5,pc1_6,pc1_7;
    float pc3_0,pc3_1,pc3_2,pc3_3,pc3_4,pc3_5,pc3_6,pc3_7;
    {
        const float e7x = ax0 - ax7, e7y = ay0 - ay7;   // ea_7
#define SEED(J) { \
        float Dx = bx##J - ax7, Dy = by##J - ay7; \
        pc1_##J = Dx*e7y - Dy*e7x; \
        float Ex = bx##J - ax0, Ey = by##J - ay0; \
        pc3_##J = Ex*eby##J - Ey*ebx##J; }
        SEED(0) SEED(1) SEED(2) SEED(3) SEED(4) SEED(5) SEED(6) SEED(7)
    }

    // One pair: c1/c3 forwarded (no D). pc1_J <- c1 (this row's, for next
    // row's c2); pc3_J <- c3+ee (next row's c3); c4 rolls via local (this
    // row's previous c3); c1 += ee at end (next pair, same row).
#define PAIR(J) { \
        float ee = ebx##J*reay - eby##J*reax; \
        float rr = __builtin_amdgcn_rcpf(ee); \
        float c3 = pc3_##J; \
        float c2 = pc1_##J; \
        pc1_##J = c1; \
        pc3_##J = c3 + ee; \
        float h = ee * 1e38f; \
        float tc1 = -c3 * rr; \
        t0a = fmaxf(t0a, fminf(tc1, h)); \
        t1a = fminf(t1a, fmaxf(tc1, h)); \
        float tc2 = -c1 * rr; \
        t0b##J = fmaxf(t0b##J, fminf(tc2, -h)); \
        t1b##J = fminf(t1b##J, fmaxf(tc2, -h)); \
        mbmin##J = fminf(mbmin##J, c3); \
        rmax = fmaxf(rmax, c1); \
        float mn = fminf(fminf(fminf(c1, -c2), c3), -c4); \
        float mx = fmaxf(fmaxf(fmaxf(c1, -c2), c3), -c4); \
        float cx = rax*by##J - ray*bx##J; \
        hbp += (mn >= 0.f) ? cx : 0.f; \
        hbm += (mx <= 0.f) ? cx : 0.f; \
        c4 = c3; \
        c1 += ee; }

    // Row for A-edge i (laundered A_i, r24-proven anti-hoist).
    // c4 init = pc3_7 = c3(i,7) (identity, exact); c1 seed direct.
#define ROW(I,IN) { \
        float rax = ax##I, ray = ay##I; \
        asm volatile("" : "+v"(rax), "+v"(ray) : "v"(hbp), "v"(hbm)); \
        const float reax = ax##IN - rax, reay = ay##IN - ray; \
        float t0a = 0.f, t1a = 1.f, rmax = -1e38f; \
        float c1 = (bx0 - rax)*reay - (by0 - ray)*reax; \
        float c4 = pc3_7; \
        PAIR(0) PAIR(1) PAIR(2) PAIR(3) \
        PAIR(4) PAIR(5) PAIR(6) PAIR(7) \
        float cai = rax*ay##IN - ray*ax##IN; \
        areaA2 += cai; \
        float dt = t1a - t0a; \
        inter2 += fmaxf(dt, 0.f) * cai; \
        eSa += (rmax <= 0.f) ? cai : 0.f; }

    ROW(0,1) ROW(1,2) ROW(2,3) ROW(3,4)
    ROW(4,5) ROW(5,6) ROW(6,7) ROW(7,0)

    // B-edge tails: shoelace cb_j + clipped Green's term + hull mask term.
    float areaB2 = 0.f, eSb = 0.f;
#define BTAIL(J,JN) { \
        float cbj = bx##J*by##JN - by##J*bx##JN; \
        areaB2 += cbj; \
        float dt = t1b##J - t0b##J; \
        inter2 += fmaxf(dt, 0.f) * cbj; \
        eSb += (mbmin##J >= 0.f) ? cbj : 0.f; }
    BTAIL(0,1) BTAIL(1,2) BTAIL(2,3) BTAIL(3,4)
    BTAIL(4,5) BTAIL(5,6) BTAIL(6,7) BTAIL(7,0)

    float inter = fmaxf(0.5f * inter2, 0.f);
    float uni = 0.5f * areaA2 + 0.5f * areaB2 - inter;
    float iou = __fdividef(inter, uni);
    float ch = 0.5f * ((eSa + eSb) + (hbp - hbm));

    float val = iou - __fdividef(ch - uni, ch);
    float v = live ? val : 0.f;

    // ---- epilogue: shuffle -> LDS(16B) -> ONE plain store. Zero waits. ----
    #pragma unroll
    for (int off = 32; off > 0; off >>= 1) v += __shfl_down(v, off);
    __shared__ float wsum[4];
    int lane = t & 63, wid = t >> 6;
    if (lane == 0) wsum[wid] = v;
    __syncthreads();
    if (t == 0) {
        partial[blockIdx.x] = (double)wsum[0] + (double)wsum[1]
                            + (double)wsum[2] + (double)wsum[3];
    }
}

__global__ __launch_bounds__(256) void ciou_finalize(
    const double* __restrict__ partial, float* __restrict__ out,
    int nparts, int nbatch)
{
    double v = 0.0;
    for (int j = threadIdx.x; j < nparts; j += 256) v += partial[j];
    #pragma unroll
    for (int off = 32; off > 0; off >>= 1) v += __shfl_down(v, off);
    __shared__ double s[4];
    int lane = threadIdx.x & 63, wid = threadIdx.x >> 6;
    if (lane == 0) s[wid] = v;
    __syncthreads();
    if (threadIdx.x == 0)
        out[0] = (float)((s[0] + s[1] + s[2] + s[3]) / (double)nbatch);
}

extern "C" void kernel_launch(void* const* d_in, const int* in_sizes, int n_in,
                              void* d_out, int out_size, void* d_ws, size_t ws_size,
                              hipStream_t stream) {
    const float* a = (const float*)d_in[0];
    const float* b = (const float*)d_in[1];
    float* out = (float*)d_out;
    int nbatch = in_sizes[0] / 16;
    int nblocks = (nbatch + TPB - 1) / TPB;   // 262144 -> 1024, exact
    int tail = (nblocks * TPB != nbatch) ? 1 : 0;
    double* partial = (double*)d_ws;   // fully overwritten each call; no memset
    ciou_main<<<nblocks, TPB, 0, stream>>>(a, b, partial, nbatch, tail);
    ciou_finalize<<<1, 256, 0, stream>>>(partial, out, nblocks, nbatch);
}